// Round 1
// baseline (402.921 us; speedup 1.0000x reference)
//
#include <hip/hip_runtime.h>

// Problem constants (from reference)
#define MIN_LEN_SEG_C 19
#define MAX_NUM_SEG_C 7     // 128 // 19 + 1
#define MAX_LEN_PAD_C 192
#define C_DIM         80
#define NQ            (C_DIM / 4)            // 20 float4 per frame
#define NTHREADS      448                    // 7 waves
#define TOTAL_Q       (MAX_LEN_PAD_C * NQ)   // 3840
#define NITER         ((TOTAL_Q + NTHREADS - 1) / NTHREADS)  // 9 (last partial)
#define ROW_BYTES     (C_DIM * 4)            // 320 B per frame
#define BLOCK_CHUNK   (NTHREADS * 16)        // 7168 B staged per round
#define MAX_ROUNDS    6                      // ceil(128*320 / 7168)
#define SX_FLOATS     (MAX_ROUNDS * BLOCK_CHUNK / 4)  // 10752 floats = 43008 B

typedef float floatx4 __attribute__((ext_vector_type(4)));

// One block per batch row. 448 threads = 7 waves; wave w handles segment w,
// lane i handles grid position i (SEG_GRID == 64 == wavefront size).
//
// v2: LDS-stage the block's entire source window (rows 0..lseq-1, contiguous,
// <= 40 KB) via global_load_lds issued BEFORE the index computation, so the
// HBM read overlaps Phase A and each source byte is fetched exactly once.
// Segment metadata comes from uniform scalar loads (s_load) instead of an
// LDS round-trip, cutting barriers 3 -> 2.
__global__ __launch_bounds__(NTHREADS) void interp_lnr_kernel(
    const float* __restrict__ x,          // (B, 192, 80)
    const int*   __restrict__ len_seq,    // (B,)
    const float* __restrict__ scales,     // (B*7,)
    const int*   __restrict__ len_seg_raw,// (B*7,)
    float*       __restrict__ out)        // (B, 192, 80)
{
    const int b    = blockIdx.x;
    const int tid  = threadIdx.x;
    const int wave = tid >> 6;   // segment index 0..6
    const int lane = tid & 63;   // grid index 0..63

    __shared__ float s_x[SX_FLOATS];          // staged source frames
    __shared__ int   s_src[MAX_LEN_PAD_C];
    __shared__ float s_lam[MAX_LEN_PAD_C];
    __shared__ int   s_wavecnt[MAX_NUM_SEG_C];

    const int lseq = len_seq[b];   // block-uniform -> scalar load

    // ---- Stage x[b, 0:lseq, :] into LDS, 16 B/lane, linear dest ----
    // rounds is block-uniform; overshoot in the last round reads rows
    // beyond lseq (still inside the 192-row padded input) into LDS slack.
    {
        const char* gx = (const char*)(x + (size_t)b * MAX_LEN_PAD_C * C_DIM);
        char*       lx = (char*)s_x;
        const int rounds = (lseq * ROW_BYTES + BLOCK_CHUNK - 1) / BLOCK_CHUNK; // <= 6
        for (int r = 0; r < rounds; ++r) {
            const int chunk = r * BLOCK_CHUNK + wave * 1024;  // wave-uniform byte base
            __builtin_amdgcn_global_load_lds(
                (const __attribute__((address_space(1))) void*)(gx + chunk + lane * 16),
                (__attribute__((address_space(3))) void*)(lx + chunk),
                16, 0, 0);
        }
    }

    // ---- Phase A: per-(segment, grid) mask / source index / lam ----
    // Segment metadata via uniform loads (no LDS, no barrier needed).
    int lensegs[MAX_NUM_SEG_C];
    #pragma unroll
    for (int t = 0; t < MAX_NUM_SEG_C; ++t)
        lensegs[t] = len_seg_raw[b * MAX_NUM_SEG_C + t] + MIN_LEN_SEG_C;
    const float scale = scales[b * MAX_NUM_SEG_C + wave] + 0.5f;

    // offset = sum of lenseg[0..wave-1]; lenw = lenseg[wave] (static indexing)
    int offset = 0;
    int lenw   = lensegs[0];
    #pragma unroll
    for (int t = 1; t < MAX_NUM_SEG_C; ++t) {
        if (wave >= t) offset += lensegs[t - 1];
        if (wave == t) lenw    = lensegs[t];
    }

    // Bit-exact mirror of the reference's f32 arithmetic.
    const float idx_scaled = (float)lane / scale;      // IEEE f32 div
    const float idx_fl     = floorf(idx_scaled);
    const float lam        = idx_scaled - idx_fl;
    const float idx_org    = idx_fl + (float)offset;

    const bool mask = (idx_fl  < (float)lenw - 1.0f) &&
                      (idx_org < (float)(lseq - 1));

    // ---- compacted position via ballot + two-level prefix sum ----
    const unsigned long long bal = __ballot(mask);
    if (lane == 0) s_wavecnt[wave] = __popcll(bal);
    if (tid < MAX_LEN_PAD_C) s_src[tid] = -1;   // default: invalid slot -> zero
    __syncthreads();   // orders s_src init + wavecnt; drains staging vmcnt

    int wave_off = 0;
    #pragma unroll
    for (int t = 0; t < MAX_NUM_SEG_C - 1; ++t)
        if (wave > t) wave_off += s_wavecnt[t];
    const int rank = __popcll(bal & ((1ull << lane) - 1ull));

    if (mask) {
        const int pos = wave_off + rank;
        if (pos < MAX_LEN_PAD_C) {
            // mask guarantees idx_org < lseq-1 <= 127, so src <= lseq-2 and
            // src+1 is staged.
            s_src[pos] = (int)idx_org;
            s_lam[pos] = lam;
        }
    }
    __syncthreads();

    // ---- Phase B: 192 frames x 20 float4, gather from LDS, coalesced NT store ----
    floatx4* __restrict__ out4 =
        (floatx4*)(out + (size_t)b * MAX_LEN_PAD_C * C_DIM);
    const floatx4* s_x4 = (const floatx4*)s_x;

    #pragma unroll
    for (int i = 0; i < NITER; ++i) {
        const int t = tid + i * NTHREADS;
        if (t < TOTAL_Q) {
            const int p = t / NQ;           // output frame 0..191
            const int q = t - p * NQ;       // float4 lane within frame
            const int src = s_src[p];
            floatx4 r = (floatx4)(0.0f);
            if (src >= 0) {
                const float lm = s_lam[p];
                const floatx4 va = s_x4[src * NQ + q];
                const floatx4 vc = s_x4[src * NQ + q + NQ];
                r = (1.0f - lm) * va + lm * vc;
            }
            __builtin_nontemporal_store(r, &out4[t]);   // streaming write-once
        }
    }
}

extern "C" void kernel_launch(void* const* d_in, const int* in_sizes, int n_in,
                              void* d_out, int out_size, void* d_ws, size_t ws_size,
                              hipStream_t stream) {
    const float* x           = (const float*)d_in[0];
    const int*   len_seq     = (const int*)d_in[1];
    const float* scales      = (const float*)d_in[2];
    const int*   len_seg_raw = (const int*)d_in[3];
    float*       out         = (float*)d_out;

    const int B = in_sizes[1];   // len_seq has one element per batch row

    interp_lnr_kernel<<<B, NTHREADS, 0, stream>>>(x, len_seq, scales, len_seg_raw, out);
}

// Round 2
// 394.374 us; speedup vs baseline: 1.0217x; 1.0217x over previous
//
#include <hip/hip_runtime.h>

// Problem constants (from reference)
#define MIN_LEN_SEG_C 19
#define MAX_NUM_SEG_C 7     // 128 // 19 + 1
#define MAX_LEN_PAD_C 192
#define C_DIM         80
#define NQ            (C_DIM / 4)            // 20 float4 per frame
#define NTHREADS      448                    // 7 waves
#define TOTAL_Q       (MAX_LEN_PAD_C * NQ)   // 3840
#define NITER         ((TOTAL_Q + NTHREADS - 1) / NTHREADS)  // 9 (last partial)

typedef float floatx4 __attribute__((ext_vector_type(4)));

// One block per batch row. 448 threads = 7 waves; wave w owns segment w,
// lane i owns grid position i (SEG_GRID == 64 == wavefront size).
//
// v3: single-barrier structure. Every wave redundantly computes ALL 7
// segments' masks/ballots (identical across waves -> each wave locally knows
// every segment count, its own exclusive prefix, and the total T). Compaction
// is dense (mask is a lane-prefix per segment), so s_src[0..T-1] is fully
// written and no default-init pass is needed. Phase B gathers directly from
// global (src is monotone -> near-sequential, L1-friendly) and NT-stores.
__global__ __launch_bounds__(NTHREADS) void interp_lnr_kernel(
    const float* __restrict__ x,          // (B, 192, 80)
    const int*   __restrict__ len_seq,    // (B,)
    const float* __restrict__ scales,     // (B*7,)
    const int*   __restrict__ len_seg_raw,// (B*7,)
    float*       __restrict__ out)        // (B, 192, 80)
{
    const int b    = blockIdx.x;
    const int tid  = threadIdx.x;
    const int wave = tid >> 6;   // segment index 0..6
    const int lane = tid & 63;   // grid index 0..63

    __shared__ int   s_src[MAX_LEN_PAD_C];
    __shared__ float s_lam[MAX_LEN_PAD_C];

    const int lseq = len_seq[b];              // block-uniform -> s_load

    // ---- Phase A: all 7 segments computed by every wave (redundant, cheap).
    // Bit-exact mirror of the reference's f32 arithmetic.
    float scl[MAX_NUM_SEG_C];
    int   lensegs[MAX_NUM_SEG_C];
    #pragma unroll
    for (int s = 0; s < MAX_NUM_SEG_C; ++s) {
        scl[s]     = scales[b * MAX_NUM_SEG_C + s] + 0.5f;
        lensegs[s] = len_seg_raw[b * MAX_NUM_SEG_C + s] + MIN_LEN_SEG_C;
    }

    unsigned long long bal_own = 0;   // own segment's ballot
    float lam_own = 0.0f, idxorg_own = 0.0f;
    int   offset = 0;      // exclusive prefix of lenseg
    int   T = 0;           // total compacted count (uniform)
    int   wave_off = 0;    // exclusive prefix of counts for own wave

    #pragma unroll
    for (int s = 0; s < MAX_NUM_SEG_C; ++s) {
        const float idx_scaled = (float)lane / scl[s];     // IEEE f32 div
        const float idx_fl     = floorf(idx_scaled);
        const float lam        = idx_scaled - idx_fl;
        const float idx_org    = idx_fl + (float)offset;
        const bool  m = (idx_fl  < (float)lensegs[s] - 1.0f) &&
                        (idx_org < (float)(lseq - 1));
        const unsigned long long bal = __ballot(m);        // identical on all waves
        const int c = __popcll(bal);
        if (s == wave) { bal_own = bal; lam_own = lam; idxorg_own = idx_org; }
        if (s <  wave) wave_off += c;
        T += c;
        offset += lensegs[s];
    }

    // ---- dense scatter of (src, lam); positions 0..T-1 are all covered ----
    const int rank = __popcll(bal_own & ((1ull << lane) - 1ull));
    if ((bal_own >> lane) & 1ull) {
        const int pos = wave_off + rank;
        if (pos < MAX_LEN_PAD_C) {
            // mask guarantees idx_org < lseq-1 <= 127 -> src <= 126, src+1 in-bounds
            s_src[pos] = (int)idxorg_own;
            s_lam[pos] = lam_own;
        }
    }
    __syncthreads();   // the only barrier

    const int Tc = min(T, MAX_LEN_PAD_C);

    // ---- Phase B: 192 frames x 20 float4; batched near-sequential global
    // gather -> lerp -> coalesced nontemporal store (write-once streaming).
    const floatx4* __restrict__ x4 =
        (const floatx4*)(x + (size_t)b * MAX_LEN_PAD_C * C_DIM);
    floatx4* __restrict__ out4 =
        (floatx4*)(out + (size_t)b * MAX_LEN_PAD_C * C_DIM);

    int   srcs[NITER];
    float lams[NITER];
    int   qs[NITER];

    #pragma unroll
    for (int i = 0; i < NITER; ++i) {
        const int t = tid + i * NTHREADS;
        if (t < TOTAL_Q) {
            const int p = t / NQ;
            qs[i] = t - p * NQ;
            if (p < Tc) { srcs[i] = s_src[p]; lams[i] = s_lam[p]; }
            else        { srcs[i] = -1; lams[i] = 0.0f; }   // zero frame
        } else {
            srcs[i] = -2;   // past end: no store at all
            qs[i]   = 0;
            lams[i] = 0.0f;
        }
    }

    floatx4 va[NITER], vc[NITER];
    #pragma unroll
    for (int i = 0; i < NITER; ++i) {
        if (srcs[i] >= 0) {
            const int base = srcs[i] * NQ + qs[i];
            va[i] = x4[base];
            vc[i] = x4[base + NQ];
        }
    }

    #pragma unroll
    for (int i = 0; i < NITER; ++i) {
        const int t = tid + i * NTHREADS;
        if (srcs[i] >= -1) {   // t < TOTAL_Q
            floatx4 r = (floatx4)(0.0f);
            if (srcs[i] >= 0) {
                const float lm = lams[i];
                const float w0 = 1.0f - lm;
                r = w0 * va[i] + lm * vc[i];
            }
            __builtin_nontemporal_store(r, &out4[t]);
        }
    }
}

extern "C" void kernel_launch(void* const* d_in, const int* in_sizes, int n_in,
                              void* d_out, int out_size, void* d_ws, size_t ws_size,
                              hipStream_t stream) {
    const float* x           = (const float*)d_in[0];
    const int*   len_seq     = (const int*)d_in[1];
    const float* scales      = (const float*)d_in[2];
    const int*   len_seg_raw = (const int*)d_in[3];
    float*       out         = (float*)d_out;

    const int B = in_sizes[1];   // len_seq has one element per batch row

    interp_lnr_kernel<<<B, NTHREADS, 0, stream>>>(x, len_seq, scales, len_seg_raw, out);
}